// Round 4
// baseline (171.361 us; speedup 1.0000x reference)
//
#include <hip/hip_runtime.h>
#include <math.h>

#define ALPHA 8.3f
#define STAGE_BYTES 17408    // 1088 granules * 16 B (4 rows x 34 cols x 8 granules)

typedef short v8s  __attribute__((ext_vector_type(8)));
typedef float v16f __attribute__((ext_vector_type(16)));
typedef float v4f  __attribute__((ext_vector_type(4)));

static __device__ __forceinline__ unsigned short f2bf(float f) {
    unsigned int u = __float_as_uint(f);
    u = (u + 0x7fffu + ((u >> 16) & 1u)) >> 16;   // RNE
    return (unsigned short)u;
}

static __device__ __forceinline__ void async16(const void* g, void* l) {
    __builtin_amdgcn_global_load_lds(
        (const __attribute__((address_space(1))) unsigned int*)g,
        (__attribute__((address_space(3))) unsigned int*)l, 16, 0, 0);
}

// A-fragment pre-swizzle, v8 layout: wt[((ss*4 + kh*2 + mt)*18 + tap*2+p)*512 + lane*8 + j]
// -> per (wave, ss) the 18 fragments are one contiguous 18 KB region (each frag 1 KB
// contiguous = perfectly coalesced wave load). Values identical to prior layout:
// o = mt*32+(lane&31), c = ks*16+(lane>>5)*8+j, ks = kh*16+ss*2+p.
// Also zeroes the 1 KB halo buffer (block 0).
__global__ void prep_weights(const float* __restrict__ w, unsigned short* __restrict__ wt,
                             float* __restrict__ zb) {
    if (blockIdx.x == 0) zb[threadIdx.x] = 0.f;   // 256 floats = 1 KB
    int i = blockIdx.x * 256 + threadIdx.x;
    if (i >= 294912) return;
    int j    = i & 7;
    int lane = (i >> 3) & 63;
    int t    = i >> 9;          // 0..575
    int f    = t % 18;
    int g    = t / 18;          // 0..31
    int mt   = g & 1;
    int kh   = (g >> 1) & 1;
    int ss   = g >> 2;
    int tap  = f >> 1;
    int p    = f & 1;
    int ks   = kh * 16 + ss * 2 + p;
    int o = mt * 32 + (lane & 31);
    int c = ks * 16 + (lane >> 5) * 8 + j;
    wt[i] = f2bf(w[(o * 512 + c) * 9 + tap]);
}

// x fp32 NCHW -> bf16 NHWC (x2[b][h][w][c]).
// v9 FIX: v8 dropped channels 256-511 (grid 2048 only covered cq 0..3 after removing
// the cb loop). Now grid 4096, cq = bx&7 covers all 8 x 64 = 512 channels.
// Bit-identical values (same f2bf per element).
__global__ __launch_bounds__(256) void nhwc_cast(const float* __restrict__ x,
                                                 unsigned short* __restrict__ x2) {
    __shared__ float st[64][65];
    const int bx = blockIdx.x;
    const int cq = bx & 7;            // 64-ch eighth (0..7 -> ch 0..511)
    const int h  = (bx >> 3) & 63;
    const int b  = bx >> 9;
    const int tid = threadIdx.x;
    const float* xb = x + ((size_t)b * 512 + cq * 64) * 4096 + h * 64;
    unsigned short* ob = x2 + (((size_t)b * 64 + h) * 64) * 512 + cq * 64;
#pragma unroll
    for (int i = 0; i < 4; ++i) {
        const int c  = i * 16 + (tid >> 4);
        const int w4 = (tid & 15) * 4;
        const float4 v = *(const float4*)&xb[(size_t)c * 4096 + w4];
        st[c][w4]     = v.x;
        st[c][w4 + 1] = v.y;
        st[c][w4 + 2] = v.z;
        st[c][w4 + 3] = v.w;
    }
    __syncthreads();
#pragma unroll
    for (int j = 0; j < 2; ++j) {
        const int idx = j * 256 + tid;
        const int w = idx >> 3, k = idx & 7;
        unsigned short t[8];
#pragma unroll
        for (int e = 0; e < 8; ++e) t[e] = f2bf(st[k * 8 + e][w]);
        uint4 u;
        u.x = t[0] | ((unsigned)t[1] << 16);
        u.y = t[2] | ((unsigned)t[3] << 16);
        u.z = t[4] | ((unsigned)t[5] << 16);
        u.w = t[6] | ((unsigned)t[7] << 16);
        *(uint4*)&ob[(size_t)w * 512 + k * 8] = u;
    }
}

// Main v8 (unchanged from R3): 512 blocks x 512 thr, 2 blocks/CU;
// waves = mt(2) x rt(2) x kh(2), one row/wave, M=32, K=256.
// A-fragments register-prefetched per superstep (12 pre-loop + 6 in-loop,
// contiguous 18 KB/wave/ss layout), A(ss+1) issued before the barrier so the
// loads complete during the existing DMA vmcnt drain.
// Per-output accumulation order identical to v5-v7 (bit-exact).
__global__ __launch_bounds__(512, 4)
void depthconv_v8(const unsigned short* __restrict__ x2,
                  const float* __restrict__ depth,
                  const unsigned short* __restrict__ wt,
                  const float* __restrict__ zbuf,
                  float* __restrict__ out) {
    __shared__ __align__(16) char smem[2 * STAGE_BYTES];   // 34,816 B (epilogue reuses)

    // XCD-swizzled decode: xcd owns rows [xcd*8, xcd*8+8) for all (b, wtile)
    const int bx   = blockIdx.x;
    const int xcd  = bx & 7;
    const int i0   = bx >> 3;          // 0..63
    const int wt2  = i0 & 1;
    const int b    = (i0 >> 1) & 7;
    const int ht   = xcd * 4 + (i0 >> 4);   // 0..31 row-tiles (2 rows each)
    const int h0 = ht * 2, w0 = wt2 * 32;

    const int tid  = threadIdx.x;
    const int wid  = tid >> 6;         // 0..7
    const int lane = tid & 63;
    const int l31  = lane & 31;
    const int half = lane >> 5;
    const int mt   = wid & 1;
    const int rt   = (wid >> 1) & 1;   // wave's row within the 2-row tile
    const int kh   = wid >> 2;
    const int wg   = kh * 2 + mt;      // wt group 0..3

    const char* xpix = (const char*)(x2 + ((size_t)b * 4096) * 512);
    // per-(wave,ss) contiguous A region base (lane offset folded in)
    const unsigned short* wlane = wt + (size_t)lane * 8;

    v8s A[12];
    // A(ss, frag f) address: wt + ((ss*4 + wg)*18 + f)*512 + lane*8
#define LOADA(SS)                                                               \
    {                                                                           \
        const unsigned short* wp = wlane + (size_t)(((SS) * 4 + wg) * 18) * 512;\
        _Pragma("unroll")                                                       \
        for (int f = 0; f < 12; ++f) A[f] = *(const v8s*)(wp + f * 512);        \
    }

    // granule i (0..1087): slice = i>>3 (r*34+c, rows h0-1..h0+2, cols w0-1..w0+32),
    // gg = (i&7)^(slice&7); content = ch [(gg>>2)*256 + ss*32 + (gg&3)*8, +8).
    // LDS lane-linear (DMA), reads land conflict-free via the i-space XOR.
#define ISSUE(SS)                                                               \
    {                                                                           \
        const int ss_ = (SS);                                                   \
        char* bufb = smem + (ss_ & 1) * STAGE_BYTES;                            \
        _Pragma("unroll")                                                       \
        for (int it = 0; it < 3; ++it) {                                        \
            const int i = it * 512 + tid;                                       \
            if (i < 1088) {                                                     \
                const int slice = i >> 3;                                       \
                const int gg = (i & 7) ^ (slice & 7);                           \
                const int r = slice / 34;                                       \
                const int c = slice - r * 34;                                   \
                const int hh = h0 - 1 + r, ww = w0 - 1 + c;                     \
                const char* gp = (hh >= 0 && hh < 64 && ww >= 0 && ww < 64)     \
                    ? xpix + (size_t)(hh * 64 + ww) * 1024                      \
                           + (gg >> 2) * 512 + ss_ * 64 + (gg & 3) * 16        \
                    : (const char*)zbuf;                                        \
                async16(gp, bufb + (size_t)i * 16);                             \
            }                                                                   \
        }                                                                       \
    }

    LOADA(0);          // A(0) in flight during prologue
    ISSUE(0);          // DMA(0)

    // ---- gates for my single row (fp32, OOB depth = 0; verified R2) ----
    float gt[9];
    {
        const float* dp = depth + (size_t)b * 4096;
        const int hq = h0 + rt, wq = w0 + l31;
        const float d0 = dp[hq * 64 + wq];
#pragma unroll
        for (int t = 0; t < 9; ++t) {
            const int hn = hq + t / 3 - 1, wn = wq + t % 3 - 1;
            const float dn = (hn >= 0 && hn < 64 && wn >= 0 && wn < 64) ? dp[hn * 64 + wn] : 0.f;
            gt[t] = __expf(-ALPHA * fabsf(d0 - dn));
        }
    }

    v16f acc;
    v16f vzero;
#pragma unroll
    for (int r = 0; r < 16; ++r) { acc[r] = 0.f; vzero[r] = 0.f; }

    const int g0 = kh * 4 + half;        // kk=0 granule
    const int g1 = g0 + 2;               // kk=1 granule

    for (int ss = 0; ss < 8; ++ss) {
        __syncthreads();                    // drains DMA(ss) + A(ss) loads (vmcnt0)
        if (ss < 7) ISSUE(ss + 1);          // DMA(ss+1) flies under compute(ss)
        const char* bufb = smem + (ss & 1) * STAGE_BYTES;
        const unsigned short* wp = wlane + (size_t)((ss * 4 + wg) * 18) * 512;
#pragma unroll
        for (int tap = 0; tap < 9; ++tap) {
            const int di = tap / 3, dj = tap % 3;
            v8s a0, a1;
            if (tap < 6) {                   // register-prefetched
                a0 = A[tap * 2];
                a1 = A[tap * 2 + 1];
            } else {                         // in-loop, compiler hoists as regs allow
                a0 = *(const v8s*)(wp + (tap * 2) * 512);
                a1 = *(const v8s*)(wp + (tap * 2 + 1) * 512);
            }
            const int slice = (rt + di) * 34 + l31 + dj;
            const int s7 = slice & 7;
            const v8s b0 = *(const v8s*)(bufb + ((size_t)(slice * 8 + (g0 ^ s7))) * 16);
            const v8s b1 = *(const v8s*)(bufb + ((size_t)(slice * 8 + (g1 ^ s7))) * 16);
            v16f pass = __builtin_amdgcn_mfma_f32_32x32x16_bf16(a0, b0, vzero, 0, 0, 0);
            pass = __builtin_amdgcn_mfma_f32_32x32x16_bf16(a1, b1, pass, 0, 0, 0);
            const float gv = gt[tap];
#pragma unroll
            for (int r = 0; r < 16; ++r)
                acc[r] = fmaf(gv, pass[r], acc[r]);
        }
        if (ss < 7) LOADA(ss + 1);          // issues before barrier; completes in drain
    }

    // ---- in-block kh reduction (LDS reuses stage buffers), out written once ----
    __syncthreads();
    float* red = (float*)smem;
    const int region = mt * 2 + rt;        // 0..3, 4 KB each (16 KB of 34.8 KB)
    if (kh == 1) {
#pragma unroll
        for (int qd = 0; qd < 4; ++qd) {
            v4f v;
            v[0] = acc[qd * 4];     v[1] = acc[qd * 4 + 1];
            v[2] = acc[qd * 4 + 2]; v[3] = acc[qd * 4 + 3];
            *(v4f*)&red[region * 1024 + lane * 16 + qd * 4] = v;
        }
    }
    __syncthreads();
    if (kh == 0) {
        float* ob = out + ((size_t)b * 64) * 4096 + (h0 + rt) * 64 + w0;
#pragma unroll
        for (int qd = 0; qd < 4; ++qd) {
            const v4f v = *(const v4f*)&red[region * 1024 + lane * 16 + qd * 4];
#pragma unroll
            for (int j = 0; j < 4; ++j) {
                const int rg = qd * 4 + j;
                const int o = mt * 32 + (rg & 3) + 8 * (rg >> 2) + 4 * half;  // verified C-layout
                ob[(size_t)o * 4096 + l31] = acc[rg] + v[j];
            }
        }
    }
}

extern "C" void kernel_launch(void* const* d_in, const int* in_sizes, int n_in,
                              void* d_out, int out_size, void* d_ws, size_t ws_size,
                              hipStream_t stream) {
    const float* x      = (const float*)d_in[0];
    const float* depth  = (const float*)d_in[1];
    const float* weight = (const float*)d_in[2];
    float* out = (float*)d_out;

    unsigned short* wtb = (unsigned short*)d_ws;                        // 589,824 B
    float* zbuf         = (float*)((char*)d_ws + 786432);               // 1 KB zeros (halo)
    unsigned short* x2  = (unsigned short*)((char*)d_ws + (1 << 20));   // 33.6 MB bf16 NHWC

    prep_weights<<<1152, 256, 0, stream>>>(weight, wtb, zbuf);   // also zeroes zbuf
    nhwc_cast<<<4096, 256, 0, stream>>>(x, x2);
    depthconv_v8<<<512, 512, 0, stream>>>(x2, depth, wtb, zbuf, out);
}

// Round 5
// 157.511 us; speedup vs baseline: 1.0879x; 1.0879x over previous
//
#include <hip/hip_runtime.h>
#include <math.h>

#define ALPHA 8.3f
#define STAGE_BYTES 26112   // 1632 granules * 16 B (3 rows x 34 cols x 16 granules of 8ch)

typedef short v8s  __attribute__((ext_vector_type(8)));
typedef float v16f __attribute__((ext_vector_type(16)));
typedef float v4f  __attribute__((ext_vector_type(4)));

static __device__ __forceinline__ unsigned short f2bf(float f) {
    unsigned int u = __float_as_uint(f);
    u = (u + 0x7fffu + ((u >> 16) & 1u)) >> 16;   // RNE
    return (unsigned short)u;
}

static __device__ __forceinline__ void async16(const void* g, void* l) {
    __builtin_amdgcn_global_load_lds(
        (const __attribute__((address_space(1))) unsigned int*)g,
        (__attribute__((address_space(3))) unsigned int*)l, 16, 0, 0);
}

// A-fragment pre-swizzle, v10 layout:
// F = ((ss*2 + mt)*9 + tap)*8 + chunk   (ss:0..3 = 128-ch superstep, chunk:0..7 = 16-ch)
// wt[F*512 + lane*8 + j] ; o = mt*32+(lane&31), cin = ss*128 + chunk*16 + (lane>>5)*8 + j
// Per (wave, ss): 24 contiguous KB (3 taps x 8 chunks x 1 KB), coalesced 1 KB per load.
// Also zeroes the 1 KB halo buffer (block 0).
__global__ void prep_weights(const float* __restrict__ w, unsigned short* __restrict__ wt,
                             float* __restrict__ zb) {
    if (blockIdx.x == 0) zb[threadIdx.x] = 0.f;   // 256 floats = 1 KB
    int i = blockIdx.x * 256 + threadIdx.x;
    if (i >= 294912) return;
    int j     = i & 7;
    int lane  = (i >> 3) & 63;
    int F     = i >> 9;          // 0..575
    int chunk = F & 7;
    int t     = F >> 3;          // 0..71
    int tap   = t % 9;
    int sm    = t / 9;           // 0..7
    int mt    = sm & 1;
    int ss    = sm >> 1;         // 0..3
    int o   = mt * 32 + (lane & 31);
    int cin = ss * 128 + chunk * 16 + (lane >> 5) * 8 + j;
    wt[i] = f2bf(w[(o * 512 + cin) * 9 + tap]);
}

// x fp32 NCHW -> bf16 NHWC (x2[b][h][w][c]). Unchanged from R4 (correct, 4096 blocks).
__global__ __launch_bounds__(256) void nhwc_cast(const float* __restrict__ x,
                                                 unsigned short* __restrict__ x2) {
    __shared__ float st[64][65];
    const int bx = blockIdx.x;
    const int cq = bx & 7;            // 64-ch eighth (0..7 -> ch 0..511)
    const int h  = (bx >> 3) & 63;
    const int b  = bx >> 9;
    const int tid = threadIdx.x;
    const float* xb = x + ((size_t)b * 512 + cq * 64) * 4096 + h * 64;
    unsigned short* ob = x2 + (((size_t)b * 64 + h) * 64) * 512 + cq * 64;
#pragma unroll
    for (int i = 0; i < 4; ++i) {
        const int c  = i * 16 + (tid >> 4);
        const int w4 = (tid & 15) * 4;
        const float4 v = *(const float4*)&xb[(size_t)c * 4096 + w4];
        st[c][w4]     = v.x;
        st[c][w4 + 1] = v.y;
        st[c][w4 + 2] = v.z;
        st[c][w4 + 3] = v.w;
    }
    __syncthreads();
#pragma unroll
    for (int j = 0; j < 2; ++j) {
        const int idx = j * 256 + tid;
        const int w = idx >> 3, k = idx & 7;
        unsigned short t[8];
#pragma unroll
        for (int e = 0; e < 8; ++e) t[e] = f2bf(st[k * 8 + e][w]);
        uint4 u;
        u.x = t[0] | ((unsigned)t[1] << 16);
        u.y = t[2] | ((unsigned)t[3] << 16);
        u.z = t[4] | ((unsigned)t[5] << 16);
        u.w = t[6] | ((unsigned)t[7] << 16);
        *(uint4*)&ob[(size_t)w * 512 + k * 8] = u;
    }
}

// Main v10: 1024 blocks x 384 thr (6 waves = mt(2) x di(3)), 2 blocks/CU.
// Block = (b, 1 row, 32 cols), all 64 Cout, full K=512 in 4 supersteps of 128 ch.
// Wave (mt,di) owns kernel-row di's 3 taps, accumulating FULL K into acc[3] via the
// MFMA C-operand (no per-ss gate merge -- the v5-v8 inner-loop VALU ladder is gone).
// Gate applied once per tap in the epilogue, then 3-way di reduction in LDS.
__global__ __launch_bounds__(384, 3)
void depthconv_v10(const unsigned short* __restrict__ x2,
                   const float* __restrict__ depth,
                   const unsigned short* __restrict__ wt,
                   const float* __restrict__ zbuf,
                   float* __restrict__ out) {
    __shared__ __align__(16) char smem[2 * STAGE_BYTES];   // 52,224 B (epilogue reuses)

    // XCD-swizzled decode: xcd owns rows [xcd*8, xcd*8+8) for all (b, wtile)
    const int bx   = blockIdx.x;
    const int xcd  = bx & 7;
    const int i0   = bx >> 3;          // 0..127
    const int wt2  = i0 & 1;
    const int b    = (i0 >> 1) & 7;
    const int h0   = xcd * 8 + (i0 >> 4);   // 0..63
    const int w0   = wt2 * 32;

    const int tid  = threadIdx.x;
    const int wid  = tid >> 6;         // 0..5
    const int lane = tid & 63;
    const int l31  = lane & 31;
    const int half = lane >> 5;
    const int mt   = wid & 1;
    const int di   = wid >> 1;         // kernel row 0..2

    const char* xpix = (const char*)(x2 + ((size_t)b * 4096) * 512);

    // ---- gates for my 3 taps (fp32, OOB depth = 0; verified R2 convention) ----
    float gt[3];
    {
        const float* dp = depth + (size_t)b * 4096;
        const float d0 = dp[h0 * 64 + w0 + l31];
        const int hn = h0 + di - 1;
#pragma unroll
        for (int dj = 0; dj < 3; ++dj) {
            const int wn = w0 + l31 + dj - 1;
            const float dn = (hn >= 0 && hn < 64 && wn >= 0 && wn < 64) ? dp[hn * 64 + wn] : 0.f;
            gt[dj] = __expf(-ALPHA * fabsf(d0 - dn));
        }
    }

    v16f acc[3];
#pragma unroll
    for (int d = 0; d < 3; ++d)
#pragma unroll
        for (int r = 0; r < 16; ++r) acc[d][r] = 0.f;

    // granule i (0..1631): slice = i>>4 (r*34+c, rows h0-1..h0+1, cols w0-1..w0+32),
    // slot = i&15; content granule g = slot ^ (slice&7), bytes [ss*256 + g*16, +16)
    // of pixel (r,c). LDS lane-linear (DMA requirement); reads undo the XOR.
#define ISSUE(SS)                                                               \
    {                                                                           \
        const int ss_ = (SS);                                                   \
        char* bufb = smem + (ss_ & 1) * STAGE_BYTES;                            \
        _Pragma("unroll")                                                       \
        for (int it = 0; it < 5; ++it) {                                        \
            const int i = it * 384 + tid;                                       \
            if (i < 1632) {                                                     \
                const int slice = i >> 4;                                       \
                const int g = (i & 15) ^ (slice & 7);                           \
                const int r = slice / 34;                                       \
                const int c = slice - r * 34;                                   \
                const int hh = h0 - 1 + r, ww = w0 - 1 + c;                     \
                const char* gp = (hh >= 0 && hh < 64 && ww >= 0 && ww < 64)     \
                    ? xpix + (size_t)(hh * 64 + ww) * 1024 + ss_ * 256 + g * 16 \
                    : (const char*)zbuf;                                        \
                async16(gp, bufb + (size_t)i * 16);                             \
            }                                                                   \
        }                                                                       \
    }

    ISSUE(0);

    for (int ss = 0; ss < 4; ++ss) {
        __syncthreads();                    // drains DMA(ss) (vmcnt0) + fences prev compute
        if (ss < 3) ISSUE(ss + 1);          // DMA(ss+1) flies under compute(ss)
        const char* bufb = smem + (ss & 1) * STAGE_BYTES;
        // wave's A region: 24 contiguous KB = 3 taps x 8 chunks x 1 KB
        const unsigned short* wp =
            wt + (size_t)(((ss * 2 + mt) * 9 + di * 3) * 8) * 512 + (size_t)lane * 8;
#pragma unroll
        for (int dj = 0; dj < 3; ++dj) {
            const int slice = di * 34 + l31 + dj;
            const int s7 = slice & 7;
#pragma unroll
            for (int ch = 0; ch < 8; ++ch) {
                const v8s a = *(const v8s*)(wp + (size_t)(dj * 8 + ch) * 512);
                const int slot = (ch * 2 + half) ^ s7;
                const v8s bb = *(const v8s*)(bufb + (size_t)(slice * 16 + slot) * 16);
                acc[dj] = __builtin_amdgcn_mfma_f32_32x32x16_bf16(a, bb, acc[dj], 0, 0, 0);
            }
        }
    }

    // ---- epilogue: gate-combine per tap, then 3-way di reduction in LDS ----
    float m[16];
#pragma unroll
    for (int r = 0; r < 16; ++r) {
        m[r] = gt[0] * acc[0][r];
        m[r] = fmaf(gt[1], acc[1][r], m[r]);
        m[r] = fmaf(gt[2], acc[2][r], m[r]);
    }

    __syncthreads();
    float* red = (float*)smem;
    if (di > 0) {
        const int region = mt * 2 + (di - 1);   // 0..3, 4 KB each
#pragma unroll
        for (int qd = 0; qd < 4; ++qd) {
            v4f v;
            v[0] = m[qd * 4];     v[1] = m[qd * 4 + 1];
            v[2] = m[qd * 4 + 2]; v[3] = m[qd * 4 + 3];
            *(v4f*)&red[(size_t)region * 1024 + lane * 16 + qd * 4] = v;
        }
    }
    __syncthreads();
    if (di == 0) {
        float* ob = out + ((size_t)b * 64) * 4096 + h0 * 64 + w0;
#pragma unroll
        for (int qd = 0; qd < 4; ++qd) {
            const v4f v1 = *(const v4f*)&red[(size_t)(mt * 2) * 1024 + lane * 16 + qd * 4];
            const v4f v2 = *(const v4f*)&red[(size_t)(mt * 2 + 1) * 1024 + lane * 16 + qd * 4];
#pragma unroll
            for (int j = 0; j < 4; ++j) {
                const int rg = qd * 4 + j;
                const int o = mt * 32 + (rg & 3) + 8 * (rg >> 2) + 4 * half;  // verified C-layout
                ob[(size_t)o * 4096 + l31] = m[rg] + v1[j] + v2[j];
            }
        }
    }
}

extern "C" void kernel_launch(void* const* d_in, const int* in_sizes, int n_in,
                              void* d_out, int out_size, void* d_ws, size_t ws_size,
                              hipStream_t stream) {
    const float* x      = (const float*)d_in[0];
    const float* depth  = (const float*)d_in[1];
    const float* weight = (const float*)d_in[2];
    float* out = (float*)d_out;

    unsigned short* wtb = (unsigned short*)d_ws;                        // 589,824 B
    float* zbuf         = (float*)((char*)d_ws + 786432);               // 1 KB zeros (halo)
    unsigned short* x2  = (unsigned short*)((char*)d_ws + (1 << 20));   // 33.6 MB bf16 NHWC

    prep_weights<<<1152, 256, 0, stream>>>(weight, wtb, zbuf);   // also zeroes zbuf
    nhwc_cast<<<4096, 256, 0, stream>>>(x, x2);
    depthconv_v10<<<1024, 384, 0, stream>>>(x2, depth, wtb, zbuf, out);
}

// Round 6
// 132.527 us; speedup vs baseline: 1.2930x; 1.1885x over previous
//
#include <hip/hip_runtime.h>
#include <math.h>

#define ALPHA 8.3f
// Per superstep (16 ch): X = 2 granule-planes x 264 slices (4 rows x 66 cols) = 528 granules
// W = 18 frags (9 taps x 2 mt) x 64 lanes = 1152 granules. Granule = 16 B.
#define XSZ   8448
#define WSZ   18432
#define BUFSZ 26880   // XSZ + WSZ; double-buffered -> 53,760 B LDS

typedef short v8s  __attribute__((ext_vector_type(8)));
typedef float v16f __attribute__((ext_vector_type(16)));
typedef float v4f  __attribute__((ext_vector_type(4)));

static __device__ __forceinline__ unsigned short f2bf(float f) {
    unsigned int u = __float_as_uint(f);
    u = (u + 0x7fffu + ((u >> 16) & 1u)) >> 16;   // RNE
    return (unsigned short)u;
}

static __device__ __forceinline__ void async16(const void* g, void* l) {
    __builtin_amdgcn_global_load_lds(
        (const __attribute__((address_space(1))) unsigned int*)g,
        (__attribute__((address_space(3))) unsigned int*)l, 16, 0, 0);
}

// v11 weight layout: granule index = (ss*18 + tap*2 + mt)*64 + lane, element j.
// Value (verified mapping): o = mt*32+(lane&31), cin = ss*16+(lane>>5)*8+j, tap.
// Main kernel DMA-copies 18,432 B linearly per ss. Also zeroes the 1 KB halo buffer.
__global__ void prep_weights(const float* __restrict__ w, unsigned short* __restrict__ wt,
                             float* __restrict__ zb) {
    if (blockIdx.x == 0) zb[threadIdx.x] = 0.f;   // 256 floats = 1 KB
    int i = blockIdx.x * 256 + threadIdx.x;
    if (i >= 294912) return;
    int j    = i & 7;
    int lane = (i >> 3) & 63;
    int F    = i >> 9;           // 0..575
    int mt   = F & 1;
    int t    = F >> 1;           // 0..287
    int tap  = t % 9;
    int ss   = t / 9;            // 0..31
    int o   = mt * 32 + (lane & 31);
    int cin = ss * 16 + (lane >> 5) * 8 + j;
    wt[i] = f2bf(w[(o * 512 + cin) * 9 + tap]);
}

// x fp32 NCHW -> bf16 NHWC (x2[b][h][w][c]). Unchanged (correct since R4).
__global__ __launch_bounds__(256) void nhwc_cast(const float* __restrict__ x,
                                                 unsigned short* __restrict__ x2) {
    __shared__ float st[64][65];
    const int bx = blockIdx.x;
    const int cq = bx & 7;            // 64-ch eighth
    const int h  = (bx >> 3) & 63;
    const int b  = bx >> 9;
    const int tid = threadIdx.x;
    const float* xb = x + ((size_t)b * 512 + cq * 64) * 4096 + h * 64;
    unsigned short* ob = x2 + (((size_t)b * 64 + h) * 64) * 512 + cq * 64;
#pragma unroll
    for (int i = 0; i < 4; ++i) {
        const int c  = i * 16 + (tid >> 4);
        const int w4 = (tid & 15) * 4;
        const float4 v = *(const float4*)&xb[(size_t)c * 4096 + w4];
        st[c][w4]     = v.x;
        st[c][w4 + 1] = v.y;
        st[c][w4 + 2] = v.z;
        st[c][w4 + 3] = v.w;
    }
    __syncthreads();
#pragma unroll
    for (int j = 0; j < 2; ++j) {
        const int idx = j * 256 + tid;
        const int w = idx >> 3, k = idx & 7;
        unsigned short t[8];
#pragma unroll
        for (int e = 0; e < 8; ++e) t[e] = f2bf(st[k * 8 + e][w]);
        uint4 u;
        u.x = t[0] | ((unsigned)t[1] << 16);
        u.y = t[2] | ((unsigned)t[3] << 16);
        u.z = t[4] | ((unsigned)t[5] << 16);
        u.w = t[6] | ((unsigned)t[7] << 16);
        *(uint4*)&ob[(size_t)w * 512 + k * 8] = u;
    }
}

// Main v11: 256 blocks x 384 thr (6 waves = rt(2) x di(3)), 1 block/CU, one round.
// Block = (b, 2 rows, full 64-col row), all 64 Cout, K=512 over 32 supersteps of 16 ch.
// BOTH operands LDS-staged via global_load_lds (weights too -- no in-loop global loads).
// Wave (rt,di): acc[3 dj][2 n][2 mt] (192 VGPR) -> 12 indep MFMA chains, each a/b
// ds_read feeds 2 MFMAs (1.0 reads/MFMA). Channel-major X layout -> all ds_read_b128
// 32-lane contiguous (conflict-free, no XOR swizzle needed).
// Gate applied once per tap in epilogue (v10 algebra); di-reduction via LDS RMW.
__global__ __launch_bounds__(384, 2)
void depthconv_v11(const unsigned short* __restrict__ x2,
                   const float* __restrict__ depth,
                   const unsigned short* __restrict__ wt,
                   const float* __restrict__ zbuf,
                   float* __restrict__ out) {
    __shared__ __align__(16) char smem[2 * BUFSZ];   // 53,760 B (epilogue reuses)

    // XCD-swizzled decode: xcd owns row-tiles [xcd*4, xcd*4+4) for all b
    const int bx   = blockIdx.x;
    const int xcd  = bx & 7;
    const int i0   = bx >> 3;            // 0..31
    const int b    = i0 & 7;
    const int h0   = (xcd * 4 + (i0 >> 3)) * 2;   // 0..62, 2 rows per block

    const int tid  = threadIdx.x;
    const int wid  = tid >> 6;           // 0..5
    const int lane = tid & 63;
    const int l31  = lane & 31;
    const int half = lane >> 5;
    const int rt   = wid & 1;            // wave's row within the 2-row tile
    const int di   = wid >> 1;           // kernel row 0..2

    const char* xpix = (const char*)(x2 + ((size_t)b * 4096) * 512);

    // ---- X-DMA source pointers (ss-invariant part; advance += 32 B per ss) ----
    // dest granule i (0..527): g = i/264 (8-ch plane), slice = i%264 = r*66 + c;
    // pixel (h0-1+r, c-1); src = pix*1024 + ss*32 + g*16. OOB -> zbuf (reads zeros;
    // zbuf advance 31*32+16 = 1008 <= 1024 B, safe).
    const char* p0;
    const char* p1;
    {
        const int i_0 = tid;
        const int g_0 = (i_0 >= 264) ? 1 : 0;
        const int s_0 = i_0 - g_0 * 264;
        const int r_0 = s_0 / 66, c_0 = s_0 - r_0 * 66;
        const int hh0 = h0 - 1 + r_0, ww0 = c_0 - 1;
        p0 = (hh0 >= 0 && hh0 < 64 && ww0 >= 0 && ww0 < 64)
                 ? xpix + (size_t)(hh0 * 64 + ww0) * 1024 + g_0 * 16
                 : (const char*)zbuf;
        const int i_1 = 384 + tid;       // only tid<144 used
        const int g_1 = (i_1 >= 264) ? 1 : 0;
        const int s_1 = i_1 - g_1 * 264;
        const int r_1 = s_1 / 66, c_1 = s_1 - r_1 * 66;
        const int hh1 = h0 - 1 + r_1, ww1 = c_1 - 1;
        p1 = (hh1 >= 0 && hh1 < 64 && ww1 >= 0 && ww1 < 64)
                 ? xpix + (size_t)(hh1 * 64 + ww1) * 1024 + g_1 * 16
                 : (const char*)zbuf;
    }
    const char* wsrc = (const char*)wt;   // advances += 18432 per ss

    // W dest: linear granules [528, 1680) = bytes [XSZ, BUFSZ). 1152 = 3*384 exact.
#define ISSUE(BSEL)                                                              \
    {                                                                            \
        char* dst = smem + (BSEL) * BUFSZ;                                       \
        async16(wsrc + (size_t)tid * 16,         dst + XSZ + tid * 16);          \
        async16(wsrc + (size_t)(384 + tid) * 16, dst + XSZ + (384 + tid) * 16);  \
        async16(wsrc + (size_t)(768 + tid) * 16, dst + XSZ + (768 + tid) * 16);  \
        async16(p0, dst + tid * 16);                                             \
        if (tid < 144) async16(p1, dst + (384 + tid) * 16);                      \
        p0 += 32; p1 += 32; wsrc += 18432;                                       \
    }

    ISSUE(0);

    // ---- gates gt[n][dj] for my row (fp32, OOB depth = 0; verified convention) ----
    float gt[2][3];
    {
        const float* dp = depth + (size_t)b * 4096;
        const int hq = h0 + rt;
        const int hn = hq + di - 1;
#pragma unroll
        for (int n = 0; n < 2; ++n) {
            const int wq = n * 32 + l31;
            const float d0 = dp[hq * 64 + wq];
#pragma unroll
            for (int dj = 0; dj < 3; ++dj) {
                const int wn = wq + dj - 1;
                const float dn = (hn >= 0 && hn < 64 && wn >= 0 && wn < 64)
                                     ? dp[hn * 64 + wn] : 0.f;
                gt[n][dj] = __expf(-ALPHA * fabsf(d0 - dn));
            }
        }
    }

    v16f a00[3], a01[3], a10[3], a11[3];   // acc[dj][n][mt]: aNM, N=n, M=mt
#pragma unroll
    for (int d = 0; d < 3; ++d)
#pragma unroll
        for (int r = 0; r < 16; ++r) { a00[d][r] = 0.f; a01[d][r] = 0.f;
                                       a10[d][r] = 0.f; a11[d][r] = 0.f; }

    // per-thread LDS addr bases (buffer offset added per ss)
    const int aOff = XSZ + di * 6144 + lane * 16;                   // + (dj*2+mt)*1024
    const int bOff = (half * 264 + (rt + di) * 66 + l31) * 16;      // + (n*32+dj)*16

    for (int ss = 0; ss < 32; ++ss) {
        __syncthreads();                    // drains DMA(ss) (vmcnt0)
        const int cur = ss & 1;
        if (ss < 31) ISSUE(cur ^ 1);        // DMA(ss+1) flies under compute(ss)
        const char* ba = smem + cur * BUFSZ + aOff;
        const char* bb = smem + cur * BUFSZ + bOff;
#pragma unroll
        for (int dj = 0; dj < 3; ++dj) {
            const v8s w0 = *(const v8s*)(ba + (dj * 2 + 0) * 1024);
            const v8s w1 = *(const v8s*)(ba + (dj * 2 + 1) * 1024);
            const v8s x0 = *(const v8s*)(bb + (0 * 32 + dj) * 16);
            const v8s x1 = *(const v8s*)(bb + (1 * 32 + dj) * 16);
            a00[dj] = __builtin_amdgcn_mfma_f32_32x32x16_bf16(w0, x0, a00[dj], 0, 0, 0);
            a01[dj] = __builtin_amdgcn_mfma_f32_32x32x16_bf16(w1, x0, a01[dj], 0, 0, 0);
            a10[dj] = __builtin_amdgcn_mfma_f32_32x32x16_bf16(w0, x1, a10[dj], 0, 0, 0);
            a11[dj] = __builtin_amdgcn_mfma_f32_32x32x16_bf16(w1, x1, a11[dj], 0, 0, 0);
        }
    }

    // ---- epilogue: gate-combine per tap into [0] slot (in place) ----
#pragma unroll
    for (int r = 0; r < 16; ++r) {
        a00[0][r] = gt[0][0] * a00[0][r];
        a00[0][r] = fmaf(gt[0][1], a00[1][r], a00[0][r]);
        a00[0][r] = fmaf(gt[0][2], a00[2][r], a00[0][r]);
        a01[0][r] = gt[0][0] * a01[0][r];
        a01[0][r] = fmaf(gt[0][1], a01[1][r], a01[0][r]);
        a01[0][r] = fmaf(gt[0][2], a01[2][r], a01[0][r]);
        a10[0][r] = gt[1][0] * a10[0][r];
        a10[0][r] = fmaf(gt[1][1], a10[1][r], a10[0][r]);
        a10[0][r] = fmaf(gt[1][2], a10[2][r], a10[0][r]);
        a11[0][r] = gt[1][0] * a11[0][r];
        a11[0][r] = fmaf(gt[1][1], a11[1][r], a11[0][r]);
        a11[0][r] = fmaf(gt[1][2], a11[2][r], a11[0][r]);
    }

    // ---- di-reduction in LDS (RMW, 2 x 16 KB regions, qd-major = conflict-free) ----
    // red idx = rt*4096 + (n*2+mt)*1024 + qd*256 + lane*4   (floats)
    __syncthreads();
    float* red = (float*)smem;
    const int rbase = rt * 4096 + lane * 4;
#define EPI_STORE(ACC, N, MT)                                                    \
    _Pragma("unroll")                                                            \
    for (int qd = 0; qd < 4; ++qd) {                                             \
        v4f v; v[0] = ACC[0][qd * 4]; v[1] = ACC[0][qd * 4 + 1];                 \
        v[2] = ACC[0][qd * 4 + 2]; v[3] = ACC[0][qd * 4 + 3];                    \
        *(v4f*)&red[rbase + ((N) * 2 + (MT)) * 1024 + qd * 256] = v;             \
    }
#define EPI_ADD(ACC, N, MT)                                                      \
    _Pragma("unroll")                                                            \
    for (int qd = 0; qd < 4; ++qd) {                                             \
        v4f v = *(const v4f*)&red[rbase + ((N) * 2 + (MT)) * 1024 + qd * 256];   \
        v[0] += ACC[0][qd * 4];     v[1] += ACC[0][qd * 4 + 1];                  \
        v[2] += ACC[0][qd * 4 + 2]; v[3] += ACC[0][qd * 4 + 3];                  \
        *(v4f*)&red[rbase + ((N) * 2 + (MT)) * 1024 + qd * 256] = v;             \
    }
    if (di == 2) {
        EPI_STORE(a00, 0, 0) EPI_STORE(a01, 0, 1) EPI_STORE(a10, 1, 0) EPI_STORE(a11, 1, 1)
    }
    __syncthreads();
    if (di == 1) {
        EPI_ADD(a00, 0, 0) EPI_ADD(a01, 0, 1) EPI_ADD(a10, 1, 0) EPI_ADD(a11, 1, 1)
    }
    __syncthreads();
    if (di == 0) {
        float* ob = out + (size_t)b * 262144 + (h0 + rt) * 64;
#define EPI_OUT(ACC, N, MT)                                                      \
    _Pragma("unroll")                                                            \
    for (int qd = 0; qd < 4; ++qd) {                                             \
        const v4f v = *(const v4f*)&red[rbase + ((N) * 2 + (MT)) * 1024 + qd * 256]; \
        _Pragma("unroll")                                                        \
        for (int j = 0; j < 4; ++j) {                                            \
            const int rg = qd * 4 + j;                                           \
            const int o = (MT) * 32 + (rg & 3) + 8 * (rg >> 2) + 4 * half;       \
            ob[(size_t)o * 4096 + (N) * 32 + l31] = ACC[0][rg] + v[j];           \
        }                                                                        \
    }
        EPI_OUT(a00, 0, 0) EPI_OUT(a01, 0, 1) EPI_OUT(a10, 1, 0) EPI_OUT(a11, 1, 1)
    }
}

extern "C" void kernel_launch(void* const* d_in, const int* in_sizes, int n_in,
                              void* d_out, int out_size, void* d_ws, size_t ws_size,
                              hipStream_t stream) {
    const float* x      = (const float*)d_in[0];
    const float* depth  = (const float*)d_in[1];
    const float* weight = (const float*)d_in[2];
    float* out = (float*)d_out;

    unsigned short* wtb = (unsigned short*)d_ws;                        // 589,824 B
    float* zbuf         = (float*)((char*)d_ws + 786432);               // 1 KB zeros (halo)
    unsigned short* x2  = (unsigned short*)((char*)d_ws + (1 << 20));   // 33.6 MB bf16 NHWC

    prep_weights<<<1152, 256, 0, stream>>>(weight, wtb, zbuf);   // also zeroes zbuf
    nhwc_cast<<<4096, 256, 0, stream>>>(x, x2);
    depthconv_v11<<<256, 384, 0, stream>>>(x2, depth, wtb, zbuf, out);
}

// Round 7
// 127.765 us; speedup vs baseline: 1.3412x; 1.0373x over previous
//
#include <hip/hip_runtime.h>
#include <math.h>

#define ALPHA 8.3f
// Per superstep (32 ch): X = 4 granule-planes x 264 slices (4 rows x 66 cols) = 1056 granules
// W = 36 frags (9 taps x 2 mt x 2 kc) x 64 lanes = 2304 granules. Granule = 16 B.
#define XSZ   16896
#define WSZ   36864
#define BUFSZ 53760   // XSZ + WSZ; double-buffered -> 107,520 B LDS (gfx950: 160 KB/CU)

typedef short v8s  __attribute__((ext_vector_type(8)));
typedef float v16f __attribute__((ext_vector_type(16)));
typedef float v4f  __attribute__((ext_vector_type(4)));

static __device__ __forceinline__ unsigned short f2bf(float f) {
    unsigned int u = __float_as_uint(f);
    u = (u + 0x7fffu + ((u >> 16) & 1u)) >> 16;   // RNE
    return (unsigned short)u;
}

static __device__ __forceinline__ void async16(const void* g, void* l) {
    __builtin_amdgcn_global_load_lds(
        (const __attribute__((address_space(1))) unsigned int*)g,
        (__attribute__((address_space(3))) unsigned int*)l, 16, 0, 0);
}

// Merged prep + cast (one dispatch fewer).
// Blocks [0,4096): x fp32 NCHW -> bf16 NHWC (x2[b][h][w][c]) -- unchanged values.
// Blocks [4096,5248): weight pre-swizzle, v12 layout:
//   F = ((ss*9 + tap)*2 + mt)*2 + kc  (ss:0..15 = 32-ch superstep, kc = 16-ch chunk)
//   wt[F*512 + lane*8 + j]; o = mt*32+(lane&31), cin = ss*32 + kc*16 + (lane>>5)*8 + j
//   -> per ss one contiguous 36,864 B region, DMA-copied linearly by the main kernel.
// Block 4096 also zeroes the 1 KB halo buffer.
__global__ __launch_bounds__(256) void prep_and_cast(const float* __restrict__ x,
                                                     unsigned short* __restrict__ x2,
                                                     const float* __restrict__ w,
                                                     unsigned short* __restrict__ wt,
                                                     float* __restrict__ zb) {
    __shared__ float st[64][65];
    const int bx  = blockIdx.x;
    const int tid = threadIdx.x;
    if (bx >= 4096) {
        if (bx == 4096) zb[tid] = 0.f;    // 256 floats = 1 KB
        const int i = (bx - 4096) * 256 + tid;   // 0..294911
        const int j    = i & 7;
        const int lane = (i >> 3) & 63;
        const int F    = i >> 9;          // 0..575
        const int kc   = F & 1;
        const int mt   = (F >> 1) & 1;
        const int tq   = F >> 2;          // 0..143
        const int tap  = tq % 9;
        const int ss   = tq / 9;
        const int o    = mt * 32 + (lane & 31);
        const int cin  = ss * 32 + kc * 16 + (lane >> 5) * 8 + j;
        wt[i] = f2bf(w[(o * 512 + cin) * 9 + tap]);
        return;
    }
    const int cq = bx & 7;            // 64-ch eighth
    const int h  = (bx >> 3) & 63;
    const int b  = bx >> 9;
    const float* xb = x + ((size_t)b * 512 + cq * 64) * 4096 + h * 64;
    unsigned short* ob = x2 + (((size_t)b * 64 + h) * 64) * 512 + cq * 64;
#pragma unroll
    for (int i = 0; i < 4; ++i) {
        const int c  = i * 16 + (tid >> 4);
        const int w4 = (tid & 15) * 4;
        const float4 v = *(const float4*)&xb[(size_t)c * 4096 + w4];
        st[c][w4]     = v.x;
        st[c][w4 + 1] = v.y;
        st[c][w4 + 2] = v.z;
        st[c][w4 + 3] = v.w;
    }
    __syncthreads();
#pragma unroll
    for (int j = 0; j < 2; ++j) {
        const int idx = j * 256 + tid;
        const int ww = idx >> 3, k = idx & 7;
        unsigned short t[8];
#pragma unroll
        for (int e = 0; e < 8; ++e) t[e] = f2bf(st[k * 8 + e][ww]);
        uint4 u;
        u.x = t[0] | ((unsigned)t[1] << 16);
        u.y = t[2] | ((unsigned)t[3] << 16);
        u.z = t[4] | ((unsigned)t[5] << 16);
        u.w = t[6] | ((unsigned)t[7] << 16);
        *(uint4*)&ob[(size_t)ww * 512 + k * 8] = u;
    }
}

// Main v12: identical decomposition to v11 (256 blocks x 384 thr, 6 waves = rt(2) x di(3),
// block = (b, 2 rows, 64 cols), all 64 Cout) but 16 supersteps of 32 ch instead of 32 x 16:
// half the barrier/vmcnt(0) drains, 2x compute (24 MFMA/wave) per phase to hide the DMA.
// Both operands DMA-staged (global_load_lds); 1.0 ds_read_b128 per MFMA, conflict-free.
// Per-acc K order = exactly two chained v11 supersteps -> bit-identical numerics.
// Gate applied once per tap in epilogue; di-reduction via LDS RMW (v11-verified).
__global__ __launch_bounds__(384, 2)
void depthconv_v12(const unsigned short* __restrict__ x2,
                   const float* __restrict__ depth,
                   const unsigned short* __restrict__ wt,
                   const float* __restrict__ zbuf,
                   float* __restrict__ out) {
    __shared__ __align__(16) char smem[2 * BUFSZ];   // 107,520 B (epilogue reuses)

    // XCD-swizzled decode: xcd owns row-tiles [xcd*4, xcd*4+4) for all b
    const int bx   = blockIdx.x;
    const int xcd  = bx & 7;
    const int i0   = bx >> 3;            // 0..31
    const int b    = i0 & 7;
    const int h0   = (xcd * 4 + (i0 >> 3)) * 2;   // 0..62, 2 rows per block

    const int tid  = threadIdx.x;
    const int wid  = tid >> 6;           // 0..5
    const int lane = tid & 63;
    const int l31  = lane & 31;
    const int half = lane >> 5;
    const int rt   = wid & 1;            // wave's row within the 2-row tile
    const int di   = wid >> 1;           // kernel row 0..2

    const char* xpix = (const char*)(x2 + ((size_t)b * 4096) * 512);

    // ---- X-DMA source pointers (ss-invariant; advance += 64 B per ss) ----
    // dest granule i (0..1055): g = i/264 (8-ch plane 0..3), slice = i%264 = r*66 + c;
    // pixel (h0-1+r, c-1); src = pix*1024 + ss*64 + g*16. OOB -> zbuf
    // (max zbuf advance 15*64+48 = 1008 <= 1024 B, safe).
    const char* p0; const char* p1; const char* p2;
#define MKPTR(P, I)                                                              \
    {                                                                            \
        const int g_ = (I) / 264;                                                \
        const int s_ = (I) - g_ * 264;                                           \
        const int r_ = s_ / 66, c_ = s_ - r_ * 66;                               \
        const int hh = h0 - 1 + r_, ww = c_ - 1;                                 \
        P = (hh >= 0 && hh < 64 && ww >= 0 && ww < 64)                           \
                ? xpix + (size_t)(hh * 64 + ww) * 1024 + g_ * 16                 \
                : (const char*)zbuf;                                             \
    }
    MKPTR(p0, tid)
    MKPTR(p1, 384 + tid)
    MKPTR(p2, 768 + tid)          // used only for tid < 288
    const char* wsrc = (const char*)wt;   // advances += WSZ per ss

    // W dest: linear granules -> bytes [XSZ, BUFSZ). 2304 = 6*384 exact.
#define ISSUE(BSEL)                                                              \
    {                                                                            \
        char* dst = smem + (BSEL) * BUFSZ;                                       \
        _Pragma("unroll")                                                        \
        for (int k = 0; k < 6; ++k)                                              \
            async16(wsrc + (size_t)(k * 384 + tid) * 16,                         \
                    dst + XSZ + (k * 384 + tid) * 16);                           \
        async16(p0, dst + tid * 16);                                             \
        async16(p1, dst + (384 + tid) * 16);                                     \
        if (tid < 288) async16(p2, dst + (768 + tid) * 16);                      \
        p0 += 64; p1 += 64; p2 += 64; wsrc += WSZ;                               \
    }

    ISSUE(0);

    // ---- gates gt[n][dj] for my row (fp32, OOB depth = 0; verified convention) ----
    float gt[2][3];
    {
        const float* dp = depth + (size_t)b * 4096;
        const int hq = h0 + rt;
        const int hn = hq + di - 1;
#pragma unroll
        for (int n = 0; n < 2; ++n) {
            const int wq = n * 32 + l31;
            const float d0 = dp[hq * 64 + wq];
#pragma unroll
            for (int dj = 0; dj < 3; ++dj) {
                const int wn = wq + dj - 1;
                const float dn = (hn >= 0 && hn < 64 && wn >= 0 && wn < 64)
                                     ? dp[hn * 64 + wn] : 0.f;
                gt[n][dj] = __expf(-ALPHA * fabsf(d0 - dn));
            }
        }
    }

    v16f a00[3], a01[3], a10[3], a11[3];   // acc[dj][n][mt]: aNM, N=n, M=mt
#pragma unroll
    for (int d = 0; d < 3; ++d)
#pragma unroll
        for (int r = 0; r < 16; ++r) { a00[d][r] = 0.f; a01[d][r] = 0.f;
                                       a10[d][r] = 0.f; a11[d][r] = 0.f; }

    // per-thread LDS addr bases (buffer offset added per ss)
    // A: XSZ + (((di*3+dj)*2+mt)*2+kc)*1024 + lane*16
    const int aOff = XSZ + di * 12288 + lane * 16;
    // B: ((kc*2+half)*264 + (rt+di)*66 + (l31+n*32+dj))*16
    const int bOff = (half * 264 + (rt + di) * 66 + l31) * 16;

    for (int ss = 0; ss < 16; ++ss) {
        __syncthreads();                    // drains DMA(ss) (vmcnt0)
        const int cur = ss & 1;
        if (ss < 15) ISSUE(cur ^ 1);        // DMA(ss+1) flies under compute(ss)
        const char* ba = smem + cur * BUFSZ + aOff;
        const char* bb = smem + cur * BUFSZ + bOff;
#pragma unroll
        for (int dj = 0; dj < 3; ++dj) {
#pragma unroll
            for (int kc = 0; kc < 2; ++kc) {
                const v8s w0 = *(const v8s*)(ba + ((dj * 2 + 0) * 2 + kc) * 1024);
                const v8s w1 = *(const v8s*)(ba + ((dj * 2 + 1) * 2 + kc) * 1024);
                const v8s x0 = *(const v8s*)(bb + kc * 8448 + (0 * 32 + dj) * 16);
                const v8s x1 = *(const v8s*)(bb + kc * 8448 + (1 * 32 + dj) * 16);
                a00[dj] = __builtin_amdgcn_mfma_f32_32x32x16_bf16(w0, x0, a00[dj], 0, 0, 0);
                a01[dj] = __builtin_amdgcn_mfma_f32_32x32x16_bf16(w1, x0, a01[dj], 0, 0, 0);
                a10[dj] = __builtin_amdgcn_mfma_f32_32x32x16_bf16(w0, x1, a10[dj], 0, 0, 0);
                a11[dj] = __builtin_amdgcn_mfma_f32_32x32x16_bf16(w1, x1, a11[dj], 0, 0, 0);
            }
        }
    }

    // ---- epilogue: gate-combine per tap into [0] slot (in place) ----
#pragma unroll
    for (int r = 0; r < 16; ++r) {
        a00[0][r] = gt[0][0] * a00[0][r];
        a00[0][r] = fmaf(gt[0][1], a00[1][r], a00[0][r]);
        a00[0][r] = fmaf(gt[0][2], a00[2][r], a00[0][r]);
        a01[0][r] = gt[0][0] * a01[0][r];
        a01[0][r] = fmaf(gt[0][1], a01[1][r], a01[0][r]);
        a01[0][r] = fmaf(gt[0][2], a01[2][r], a01[0][r]);
        a10[0][r] = gt[1][0] * a10[0][r];
        a10[0][r] = fmaf(gt[1][1], a10[1][r], a10[0][r]);
        a10[0][r] = fmaf(gt[1][2], a10[2][r], a10[0][r]);
        a11[0][r] = gt[1][0] * a11[0][r];
        a11[0][r] = fmaf(gt[1][1], a11[1][r], a11[0][r]);
        a11[0][r] = fmaf(gt[1][2], a11[2][r], a11[0][r]);
    }

    // ---- di-reduction in LDS (RMW, 2 x 16 KB regions, qd-major = conflict-free) ----
    __syncthreads();
    float* red = (float*)smem;
    const int rbase = rt * 4096 + lane * 4;
#define EPI_STORE(ACC, N, MT)                                                    \
    _Pragma("unroll")                                                            \
    for (int qd = 0; qd < 4; ++qd) {                                             \
        v4f v; v[0] = ACC[0][qd * 4]; v[1] = ACC[0][qd * 4 + 1];                 \
        v[2] = ACC[0][qd * 4 + 2]; v[3] = ACC[0][qd * 4 + 3];                    \
        *(v4f*)&red[rbase + ((N) * 2 + (MT)) * 1024 + qd * 256] = v;             \
    }
#define EPI_ADD(ACC, N, MT)                                                      \
    _Pragma("unroll")                                                            \
    for (int qd = 0; qd < 4; ++qd) {                                             \
        v4f v = *(const v4f*)&red[rbase + ((N) * 2 + (MT)) * 1024 + qd * 256];   \
        v[0] += ACC[0][qd * 4];     v[1] += ACC[0][qd * 4 + 1];                  \
        v[2] += ACC[0][qd * 4 + 2]; v[3] += ACC[0][qd * 4 + 3];                  \
        *(v4f*)&red[rbase + ((N) * 2 + (MT)) * 1024 + qd * 256] = v;             \
    }
    if (di == 2) {
        EPI_STORE(a00, 0, 0) EPI_STORE(a01, 0, 1) EPI_STORE(a10, 1, 0) EPI_STORE(a11, 1, 1)
    }
    __syncthreads();
    if (di == 1) {
        EPI_ADD(a00, 0, 0) EPI_ADD(a01, 0, 1) EPI_ADD(a10, 1, 0) EPI_ADD(a11, 1, 1)
    }
    __syncthreads();
    if (di == 0) {
        float* ob = out + (size_t)b * 262144 + (h0 + rt) * 64;
#define EPI_OUT(ACC, N, MT)                                                      \
    _Pragma("unroll")                                                            \
    for (int qd = 0; qd < 4; ++qd) {                                             \
        const v4f v = *(const v4f*)&red[rbase + ((N) * 2 + (MT)) * 1024 + qd * 256]; \
        _Pragma("unroll")                                                        \
        for (int j = 0; j < 4; ++j) {                                            \
            const int rg = qd * 4 + j;                                           \
            const int o = (MT) * 32 + (rg & 3) + 8 * (rg >> 2) + 4 * half;       \
            ob[(size_t)o * 4096 + (N) * 32 + l31] = ACC[0][rg] + v[j];           \
        }                                                                        \
    }
        EPI_OUT(a00, 0, 0) EPI_OUT(a01, 0, 1) EPI_OUT(a10, 1, 0) EPI_OUT(a11, 1, 1)
    }
}

extern "C" void kernel_launch(void* const* d_in, const int* in_sizes, int n_in,
                              void* d_out, int out_size, void* d_ws, size_t ws_size,
                              hipStream_t stream) {
    const float* x      = (const float*)d_in[0];
    const float* depth  = (const float*)d_in[1];
    const float* weight = (const float*)d_in[2];
    float* out = (float*)d_out;

    unsigned short* wtb = (unsigned short*)d_ws;                        // 589,824 B
    float* zbuf         = (float*)((char*)d_ws + 786432);               // 1 KB zeros (halo)
    unsigned short* x2  = (unsigned short*)((char*)d_ws + (1 << 20));   // 33.6 MB bf16 NHWC

    prep_and_cast<<<5248, 256, 0, stream>>>(x, x2, weight, wtb, zbuf);
    depthconv_v12<<<256, 384, 0, stream>>>(x2, depth, wtb, zbuf, out);
}